// Round 19
// baseline (98.808 us; speedup 1.0000x reference)
//
#include <hip/hip_runtime.h>

#define D 64
#define K3 192  // 3*D
#define OUTD 64
#define KPB 512      // keys per bucket
#define KPB_LOG 9
#define NBMAX 256    // supports M <= 131072
#define ABATCH 4096  // edges per bin block (16 per thread)
#define CAP 8192     // staged/e_pack capacity per bucket (mean 4096, sigma 64)

typedef __attribute__((ext_vector_type(8))) short bf16x8;
typedef __attribute__((ext_vector_type(4))) float f32x4;

static __device__ __forceinline__ unsigned short f2bf(float f) {
    unsigned u = __float_as_uint(f);
    u += 0x7fffu + ((u >> 16) & 1u);  // round-to-nearest-even
    return (unsigned short)(u >> 16);
}
static __device__ __forceinline__ float bf2f(unsigned short h) {
    return __uint_as_float((unsigned)h << 16);
}

// ---------------------------------------------------------------------------
// Pass 0 (one-time): bake coef-scaled W_fc into MFMA B-fragment layout (bf16),
// convert feat -> bf16, init per-bucket staging cursors. No memsets anywhere.
// ---------------------------------------------------------------------------
__global__ __launch_bounds__(256) void prep_kernel(
        const float* __restrict__ W_fc,
        const float* __restrict__ coef_self,
        const float* __restrict__ coef_posi,
        const float* __restrict__ coef_nega,
        const float* __restrict__ feat,
        unsigned short* __restrict__ Bfrag,
        unsigned short* __restrict__ feat16,
        int* __restrict__ cursorA, int NB, int ND4) {
    int i = blockIdx.x * blockDim.x + threadIdx.x;
    if (i < NB) cursorA[i] = i * CAP;
    if (i < 6 * 4 * 64 * 8) {
        int j    = i & 7;
        int lane = (i >> 3) & 63;
        int nt   = (i >> 9) & 3;
        int kt   = i >> 11;
        int n = nt * 16 + (lane & 15);
        int k = kt * 32 + (lane >> 4) * 8 + j;
        float cf = (k < 64) ? coef_self[0] : (k < 128 ? coef_posi[0] : coef_nega[0]);
        Bfrag[i] = f2bf(W_fc[n * K3 + k] * cf);
    }
    if (i < ND4) {  // 4 feats per thread
        float4 v = *(const float4*)&feat[(size_t)i * 4];
        unsigned long long p =
            (unsigned long long)f2bf(v.x) |
            ((unsigned long long)f2bf(v.y) << 16) |
            ((unsigned long long)f2bf(v.z) << 32) |
            ((unsigned long long)f2bf(v.w) << 48);
        *(unsigned long long*)&feat16[(size_t)i * 4] = p;
    }
}

// ---------------------------------------------------------------------------
// Pass A: bin edges into fixed-capacity bucket staging.
// bucket = key >> 9, key = 2*dst + (w<0).
// Record: x = w bits, y = (src << 9) | (key & 511).
// ---------------------------------------------------------------------------
__global__ __launch_bounds__(256) void bin_kernel(
        const float* __restrict__ w, const int* __restrict__ src,
        const int* __restrict__ dst, int* __restrict__ cursorA,
        uint2* __restrict__ staged, int E, int NB) {
    __shared__ int cnt[NBMAX];
    __shared__ int base[NBMAX];
    int t = threadIdx.x;
    int e0 = blockIdx.x * ABATCH;
    for (int i = t; i < NB; i += 256) cnt[i] = 0;
    __syncthreads();

    unsigned wv[16], yv[16];
    int bk[16], rk[16];
#pragma unroll
    for (int j = 0; j < 16; ++j) {
        int e = e0 + j * 256 + t;  // coalesced per round
        if (e < E) {
            float we = w[e];
            int key = 2 * dst[e] + (we < 0.0f ? 1 : 0);
            wv[j] = __float_as_uint(we);
            yv[j] = ((unsigned)src[e] << KPB_LOG) | (unsigned)(key & (KPB - 1));
            bk[j] = key >> KPB_LOG;
            rk[j] = atomicAdd(&cnt[bk[j]], 1);
        } else {
            bk[j] = -1;
        }
    }
    __syncthreads();
    for (int b = t; b < NB; b += 256) {
        int c = cnt[b];
        if (c > 0) base[b] = atomicAdd(&cursorA[b], c);
    }
    __syncthreads();
#pragma unroll
    for (int j = 0; j < 16; ++j) {
        if (bk[j] >= 0) {
            int pos = base[bk[j]] + rk[j];
            if (pos < (bk[j] + 1) * CAP)  // defensive (60-sigma event)
                staged[pos] = make_uint2(wv[j], yv[j]);
        }
    }
}

// ---------------------------------------------------------------------------
// Pass B: per-bucket fused key-hist + scan + scatter. One block per bucket.
// Final record: x = PRECOMPUTED softmax numerator a = exp(+/-w) (f32 bits),
//               y = src.  (exp hoisted out of node_agg's latency-bound loop;
//               same f32 arithmetic -> bit-identical downstream.)
// ---------------------------------------------------------------------------
__global__ __launch_bounds__(256) void bucket_scatter_kernel(
        const int* __restrict__ cursorA, const uint2* __restrict__ staged,
        int2* __restrict__ seg_be, uint2* __restrict__ e_pack, int M) {
    __shared__ int cnt[KPB];   // counts, then cursors
    __shared__ int wt[4];
    int b = blockIdx.x;
    int t = threadIdx.x;
    int lane = t & 63;
    int wid = t >> 6;
    int kb = b << KPB_LOG;
    int nk = min(KPB, M - kb);
    int beg = b * CAP;
    int end = min(cursorA[b], beg + CAP);  // cursor = base + count

    cnt[2 * t] = 0;
    cnt[2 * t + 1] = 0;
    __syncthreads();
    for (int i = beg + t; i < end; i += 256)
        atomicAdd(&cnt[staged[i].y & (KPB - 1)], 1);
    __syncthreads();

    // block exclusive scan of 512 counts (2 per thread)
    int v0 = cnt[2 * t], v1 = cnt[2 * t + 1];
    int ps = v0 + v1;
    int incl = ps;
#pragma unroll
    for (int o = 1; o < 64; o <<= 1) {
        int u = __shfl_up(incl, o);
        if (lane >= o) incl += u;
    }
    if (lane == 63) wt[wid] = incl;
    __syncthreads();
    int wb = 0;
    for (int j = 0; j < wid; ++j) wb += wt[j];
    int excl = wb + (incl - ps);

    int p0 = beg + excl;
    int p1 = p0 + v0;
    if (2 * t < nk) seg_be[kb + 2 * t] = make_int2(p0, p1);
    if (2 * t + 1 < nk) seg_be[kb + 2 * t + 1] = make_int2(p1, p1 + v1);
    __syncthreads();
    cnt[2 * t] = p0;      // reuse as cursors
    cnt[2 * t + 1] = p1;
    __syncthreads();

    for (int i = beg + t; i < end; i += 256) {
        uint2 r = staged[i];
        int kl = (int)(r.y & (KPB - 1));
        float wv = __uint_as_float(r.x);
        float a = (kl & 1) ? __expf(-wv)                       // neg bin: w < 0
                           : ((wv > 0.0f) ? __expf(wv) : 0.0f); // pos bin: excl w==0
        int p = atomicAdd(&cnt[kl], 1);
        e_pack[p] = make_uint2(__float_as_uint(a), r.y >> KPB_LOG);
    }
}

// ---------------------------------------------------------------------------
// Pass 4: aggregation. ONE WAVE PER NODE PAIR: 4 interleaved chains
// (P0,N0,P1,N1). Per edge: wave-uniform s_load of (a, src) + one gather +
// one fmac — no exp, no sign select. Uniform clamp (e_pack[v?e:0], a=0 if
// invalid) keeps control scalar. Empty seg -> s=0 -> h=0 (matches ref).
// ---------------------------------------------------------------------------
__global__ __launch_bounds__(256) void node_agg_kernel(
        const unsigned short* __restrict__ feat16,
        const int2* __restrict__ seg_be,  // len 2N
        const uint2* __restrict__ e_pack, // x = a bits, y = src
        unsigned short* __restrict__ h_pos,
        unsigned short* __restrict__ h_neg, int N) {
    int lane = threadIdx.x & 63;
    int pr = (blockIdx.x * blockDim.x + threadIdx.x) >> 6;  // node pair
    int n0 = 2 * pr;
    if (n0 >= N) return;
    const int4* be4 = (const int4*)&seg_be[2 * n0];  // 16B-aligned
    int4 beA = be4[0];
    int eP0 = __builtin_amdgcn_readfirstlane(beA.x);
    int dP0 = __builtin_amdgcn_readfirstlane(beA.y);
    int eN0 = __builtin_amdgcn_readfirstlane(beA.z);
    int dN0 = __builtin_amdgcn_readfirstlane(beA.w);
    int eP1 = 0, dP1 = 0, eN1 = 0, dN1 = 0;
    bool has1 = (n0 + 1) < N;
    if (has1) {
        int4 beB = be4[1];
        eP1 = __builtin_amdgcn_readfirstlane(beB.x);
        dP1 = __builtin_amdgcn_readfirstlane(beB.y);
        eN1 = __builtin_amdgcn_readfirstlane(beB.z);
        dN1 = __builtin_amdgcn_readfirstlane(beB.w);
    }

    float sP0 = 0.f, aP0 = 0.f, sN0 = 0.f, aN0 = 0.f;
    float sP1 = 0.f, aP1 = 0.f, sN1 = 0.f, aN1 = 0.f;

    int len = max(max(dP0 - eP0, dN0 - eN0), max(dP1 - eP1, dN1 - eN1));
#define CHAIN(eB, dB, sAcc, vAcc)                                            \
    {                                                                        \
        int e = eB + i;                                                      \
        bool v = e < dB;                                                     \
        uint2 pk = e_pack[v ? e : 0];     /* uniform -> s_load */            \
        float a = v ? __uint_as_float(pk.x) : 0.0f;                          \
        sAcc += a;                                                           \
        vAcc = fmaf(bf2f(feat16[(size_t)(int)pk.y * D + lane]), a, vAcc);    \
    }
#pragma unroll 2
    for (int i = 0; i < len; ++i) {
        CHAIN(eP0, dP0, sP0, aP0)
        CHAIN(eN0, dN0, sN0, aN0)
        CHAIN(eP1, dP1, sP1, aP1)
        CHAIN(eN1, dN1, sN1, aN1)
    }
#undef CHAIN

    h_pos[(size_t)n0 * D + lane] = f2bf(aP0 / (sP0 + 1e-16f));
    h_neg[(size_t)n0 * D + lane] = f2bf(aN0 / (sN0 + 1e-16f));
    if (has1) {
        h_pos[(size_t)(n0 + 1) * D + lane] = f2bf(aP1 / (sP1 + 1e-16f));
        h_neg[(size_t)(n0 + 1) * D + lane] = f2bf(aN1 / (sN1 + 1e-16f));
    }
}

// ---------------------------------------------------------------------------
// Pass 5: output projection via MFMA. One wave per 16 nodes.
// A-operands are DIRECT bf16x8 loads (coef folded into Bfrag at prep).
// ---------------------------------------------------------------------------
__global__ __launch_bounds__(256) void out_gemm_mfma(
        const unsigned short* __restrict__ feat16,
        const unsigned short* __restrict__ h_pos,
        const unsigned short* __restrict__ h_neg,
        const unsigned short* __restrict__ Bfrag,
        const float* __restrict__ b_fc,
        const float* __restrict__ bias,
        float* __restrict__ out,
        int N) {
    int lane = threadIdx.x & 63;
    int wv = (blockIdx.x * blockDim.x + threadIdx.x) >> 6;
    int node0 = wv * 16;
    if (node0 >= N) return;

    const bf16x8* bp = (const bf16x8*)Bfrag;
    bf16x8 bfr[24];
#pragma unroll
    for (int f = 0; f < 24; ++f) bfr[f] = bp[f * 64 + lane];

    const unsigned short* segs[3];
    segs[0] = feat16;
    segs[1] = h_pos;
    segs[2] = h_neg;

    int m = lane & 15;          // A row / D col
    int kg = lane >> 4;         // k-group
    int node = node0 + m;
    bool mvalid = node < N;

    f32x4 acc[4];
#pragma unroll
    for (int nt = 0; nt < 4; ++nt) acc[nt] = (f32x4){0.f, 0.f, 0.f, 0.f};

#pragma unroll
    for (int kt = 0; kt < 6; ++kt) {
        int sg = kt >> 1;
        bf16x8 a;
        if (mvalid) {
            a = *(const bf16x8*)(segs[sg] + (size_t)node * D + (kt & 1) * 32 + kg * 8);
        } else {
            a = (bf16x8){0, 0, 0, 0, 0, 0, 0, 0};
        }
#pragma unroll
        for (int nt = 0; nt < 4; ++nt)
            acc[nt] = __builtin_amdgcn_mfma_f32_16x16x32_bf16(
                a, bfr[kt * 4 + nt], acc[nt], 0, 0, 0);
    }

#pragma unroll
    for (int nt = 0; nt < 4; ++nt) {
        int col = nt * 16 + m;
        float bb = b_fc[col] + bias[col];
#pragma unroll
        for (int j = 0; j < 4; ++j) {
            int row = node0 + 4 * kg + j;
            if (row < N) out[(size_t)row * OUTD + col] = acc[nt][j] + bb;
        }
    }
}

extern "C" void kernel_launch(void* const* d_in, const int* in_sizes, int n_in,
                              void* d_out, int out_size, void* d_ws, size_t ws_size,
                              hipStream_t stream) {
    const float* feat      = (const float*)d_in[0];
    const float* w         = (const float*)d_in[1];
    const float* W_fc      = (const float*)d_in[2];
    const float* b_fc      = (const float*)d_in[3];
    const float* bias      = (const float*)d_in[4];
    const float* coef_self = (const float*)d_in[5];
    const float* coef_posi = (const float*)d_in[6];
    const float* coef_nega = (const float*)d_in[7];
    const int*   src       = (const int*)d_in[8];
    const int*   dst       = (const int*)d_in[9];

    const int E = in_sizes[1];
    const int N = in_sizes[0] / D;
    const int M = 2 * N;                      // sign-split bins
    const int NB = (M + KPB - 1) / KPB;       // 196 buckets (<=256 req.)

    // Workspace layout:
    //   seg_be [M]x8B | cursorA [NB]x4 | Bfrag [12288 u16] | feat16 [N*D u16]
    //   | e_pack [NB*CAP]x8B | staged [NB*CAP]x8B | h_pos [N*D u16] | h_neg [N*D u16]
    char* ws = (char*)d_ws;
    int2*  seg_be   = (int2*)ws;
    int*   cursorA  = (int*)(ws + (size_t)M * 8);
    size_t bfrag_off = (((size_t)M * 8 + (size_t)NB * 4) + 15) & ~(size_t)15;
    unsigned short* Bfrag = (unsigned short*)(ws + bfrag_off);
    size_t feat16_off = bfrag_off + 6 * 4 * 64 * 8 * 2;
    unsigned short* feat16 = (unsigned short*)(ws + feat16_off);
    size_t epack_off = (feat16_off + (size_t)N * D * 2 + 7) & ~(size_t)7;
    uint2* e_pack  = (uint2*)(ws + epack_off);
    uint2* staged  = e_pack + (size_t)NB * CAP;
    unsigned short* h_pos = (unsigned short*)((char*)(staged + (size_t)NB * CAP));
    unsigned short* h_neg = h_pos + (size_t)N * D;

    const int ND4 = N * D / 4;
    int pb = (max(ND4, 6 * 4 * 64 * 8) + 255) / 256;
    prep_kernel<<<pb, 256, 0, stream>>>(W_fc, coef_self, coef_posi, coef_nega,
                                        feat, Bfrag, feat16, cursorA, NB, ND4);
    bin_kernel<<<(E + ABATCH - 1) / ABATCH, 256, 0, stream>>>(
        w, src, dst, cursorA, staged, E, NB);
    bucket_scatter_kernel<<<NB, 256, 0, stream>>>(cursorA, staged, seg_be,
                                                  e_pack, M);

    int npairs = (N + 1) / 2;
    int nodeb = (npairs * 64 + 255) / 256;
    node_agg_kernel<<<nodeb, 256, 0, stream>>>(feat16, seg_be, e_pack,
                                               h_pos, h_neg, N);

    int nwaves = (N + 15) / 16;
    int gb = (nwaves + 3) / 4;  // 4 waves per 256-thread block
    out_gemm_mfma<<<gb, 256, 0, stream>>>(feat16, h_pos, h_neg, Bfrag,
                                          b_fc, bias, (float*)d_out, N);
}

// Round 20
// 79.588 us; speedup vs baseline: 1.2415x; 1.2415x over previous
//
#include <hip/hip_runtime.h>

#define D 64
#define K3 192  // 3*D
#define OUTD 64
#define KPB 512      // keys per bucket
#define KPB_LOG 9
#define NBMAX 256    // supports M <= 131072
#define ABATCH 4096  // edges per bin block (16 per thread)
#define CAP 8192     // staged/e_pack capacity per bucket (mean 4096, sigma 64)

typedef __attribute__((ext_vector_type(8))) short bf16x8;
typedef __attribute__((ext_vector_type(4))) float f32x4;

static __device__ __forceinline__ unsigned short f2bf(float f) {
    unsigned u = __float_as_uint(f);
    u += 0x7fffu + ((u >> 16) & 1u);  // round-to-nearest-even
    return (unsigned short)(u >> 16);
}
static __device__ __forceinline__ float bf2f(unsigned short h) {
    return __uint_as_float((unsigned)h << 16);
}

// ---------------------------------------------------------------------------
// Pass 0 (one-time): bake coef-scaled W_fc into MFMA B-fragment layout (bf16),
// convert feat -> bf16, init per-bucket staging cursors. No memsets anywhere.
// ---------------------------------------------------------------------------
__global__ __launch_bounds__(256) void prep_kernel(
        const float* __restrict__ W_fc,
        const float* __restrict__ coef_self,
        const float* __restrict__ coef_posi,
        const float* __restrict__ coef_nega,
        const float* __restrict__ feat,
        unsigned short* __restrict__ Bfrag,
        unsigned short* __restrict__ feat16,
        int* __restrict__ cursorA, int NB, int ND4) {
    int i = blockIdx.x * blockDim.x + threadIdx.x;
    if (i < NB) cursorA[i] = i * CAP;
    if (i < 6 * 4 * 64 * 8) {
        int j    = i & 7;
        int lane = (i >> 3) & 63;
        int nt   = (i >> 9) & 3;
        int kt   = i >> 11;
        int n = nt * 16 + (lane & 15);
        int k = kt * 32 + (lane >> 4) * 8 + j;
        float cf = (k < 64) ? coef_self[0] : (k < 128 ? coef_posi[0] : coef_nega[0]);
        Bfrag[i] = f2bf(W_fc[n * K3 + k] * cf);
    }
    if (i < ND4) {  // 4 feats per thread
        float4 v = *(const float4*)&feat[(size_t)i * 4];
        unsigned long long p =
            (unsigned long long)f2bf(v.x) |
            ((unsigned long long)f2bf(v.y) << 16) |
            ((unsigned long long)f2bf(v.z) << 32) |
            ((unsigned long long)f2bf(v.w) << 48);
        *(unsigned long long*)&feat16[(size_t)i * 4] = p;
    }
}

// ---------------------------------------------------------------------------
// Pass A: bin edges into fixed-capacity bucket staging.
// bucket = key >> 9, key = 2*dst + (w<0).
// Record: x = w bits, y = (src << 9) | (key & 511).
// ---------------------------------------------------------------------------
__global__ __launch_bounds__(256) void bin_kernel(
        const float* __restrict__ w, const int* __restrict__ src,
        const int* __restrict__ dst, int* __restrict__ cursorA,
        uint2* __restrict__ staged, int E, int NB) {
    __shared__ int cnt[NBMAX];
    __shared__ int base[NBMAX];
    int t = threadIdx.x;
    int e0 = blockIdx.x * ABATCH;
    for (int i = t; i < NB; i += 256) cnt[i] = 0;
    __syncthreads();

    unsigned wv[16], yv[16];
    int bk[16], rk[16];
#pragma unroll
    for (int j = 0; j < 16; ++j) {
        int e = e0 + j * 256 + t;  // coalesced per round
        if (e < E) {
            float we = w[e];
            int key = 2 * dst[e] + (we < 0.0f ? 1 : 0);
            wv[j] = __float_as_uint(we);
            yv[j] = ((unsigned)src[e] << KPB_LOG) | (unsigned)(key & (KPB - 1));
            bk[j] = key >> KPB_LOG;
            rk[j] = atomicAdd(&cnt[bk[j]], 1);
        } else {
            bk[j] = -1;
        }
    }
    __syncthreads();
    for (int b = t; b < NB; b += 256) {
        int c = cnt[b];
        if (c > 0) base[b] = atomicAdd(&cursorA[b], c);
    }
    __syncthreads();
#pragma unroll
    for (int j = 0; j < 16; ++j) {
        if (bk[j] >= 0) {
            int pos = base[bk[j]] + rk[j];
            if (pos < (bk[j] + 1) * CAP)  // defensive (60-sigma event)
                staged[pos] = make_uint2(wv[j], yv[j]);
        }
    }
}

// ---------------------------------------------------------------------------
// Pass B: per-bucket fused key-hist + scan + scatter. One block per bucket.
// Final record: x = PRECOMPUTED softmax numerator a = exp(+/-w) (f32 bits),
//               y = src.  (exp hoisted out of node_agg's latency-bound loop.)
// ---------------------------------------------------------------------------
__global__ __launch_bounds__(256) void bucket_scatter_kernel(
        const int* __restrict__ cursorA, const uint2* __restrict__ staged,
        int2* __restrict__ seg_be, uint2* __restrict__ e_pack, int M) {
    __shared__ int cnt[KPB];   // counts, then cursors
    __shared__ int wt[4];
    int b = blockIdx.x;
    int t = threadIdx.x;
    int lane = t & 63;
    int wid = t >> 6;
    int kb = b << KPB_LOG;
    int nk = min(KPB, M - kb);
    int beg = b * CAP;
    int end = min(cursorA[b], beg + CAP);  // cursor = base + count

    cnt[2 * t] = 0;
    cnt[2 * t + 1] = 0;
    __syncthreads();
    for (int i = beg + t; i < end; i += 256)
        atomicAdd(&cnt[staged[i].y & (KPB - 1)], 1);
    __syncthreads();

    // block exclusive scan of 512 counts (2 per thread)
    int v0 = cnt[2 * t], v1 = cnt[2 * t + 1];
    int ps = v0 + v1;
    int incl = ps;
#pragma unroll
    for (int o = 1; o < 64; o <<= 1) {
        int u = __shfl_up(incl, o);
        if (lane >= o) incl += u;
    }
    if (lane == 63) wt[wid] = incl;
    __syncthreads();
    int wb = 0;
    for (int j = 0; j < wid; ++j) wb += wt[j];
    int excl = wb + (incl - ps);

    int p0 = beg + excl;
    int p1 = p0 + v0;
    if (2 * t < nk) seg_be[kb + 2 * t] = make_int2(p0, p1);
    if (2 * t + 1 < nk) seg_be[kb + 2 * t + 1] = make_int2(p1, p1 + v1);
    __syncthreads();
    cnt[2 * t] = p0;      // reuse as cursors
    cnt[2 * t + 1] = p1;
    __syncthreads();

    for (int i = beg + t; i < end; i += 256) {
        uint2 r = staged[i];
        int kl = (int)(r.y & (KPB - 1));
        float wv = __uint_as_float(r.x);
        float a = (kl & 1) ? __expf(-wv)                        // neg bin: w < 0
                           : ((wv > 0.0f) ? __expf(wv) : 0.0f); // pos: excl w==0
        int p = atomicAdd(&cnt[kl], 1);
        e_pack[p] = make_uint2(__float_as_uint(a), r.y >> KPB_LOG);
    }
}

// ---------------------------------------------------------------------------
// Pass 4: aggregation. ONE WAVE PER NODE (both sign segs, interleaved) —
// the PROVEN R18 structure (while-loops, natural early exit, no clamps),
// with exp precomputed upstream: per edge = wave-uniform s_load of (a, src)
// + one gather + one fmac + one add. Empty seg -> s=0 -> h=0 (matches ref).
// ---------------------------------------------------------------------------
__global__ __launch_bounds__(256) void node_agg_kernel(
        const unsigned short* __restrict__ feat16,
        const int2* __restrict__ seg_be,  // len 2N
        const uint2* __restrict__ e_pack, // x = a bits, y = src
        unsigned short* __restrict__ h_pos,
        unsigned short* __restrict__ h_neg, int N) {
    int lane = threadIdx.x & 63;
    int node = (blockIdx.x * blockDim.x + threadIdx.x) >> 6;
    if (node >= N) return;
    int4 be = *(const int4*)&seg_be[2 * node];  // 16B-aligned (2 int2)
    int eP   = __builtin_amdgcn_readfirstlane(be.x);
    int endP = __builtin_amdgcn_readfirstlane(be.y);
    int eN   = __builtin_amdgcn_readfirstlane(be.z);
    int endN = __builtin_amdgcn_readfirstlane(be.w);

    float sP = 0.0f, accP = 0.0f, sN = 0.0f, accN = 0.0f;

    // interleaved main loop: one pos edge + one neg edge per step (all
    // control wave-uniform; two independent dependency chains)
#pragma unroll 2
    while (eP < endP && eN < endN) {
        uint2 pkP = e_pack[eP];            // s_load
        uint2 pkN = e_pack[eN];            // s_load (independent)
        float aP = __uint_as_float(pkP.x);
        float aN = __uint_as_float(pkN.x);
        sP += aP;
        sN += aN;
        accP = fmaf(bf2f(feat16[(size_t)(int)pkP.y * D + lane]), aP, accP);
        accN = fmaf(bf2f(feat16[(size_t)(int)pkN.y * D + lane]), aN, accN);
        ++eP;
        ++eN;
    }
    // tails
#pragma unroll 4
    while (eP < endP) {
        uint2 pk = e_pack[eP];
        float aj = __uint_as_float(pk.x);
        sP += aj;
        accP = fmaf(bf2f(feat16[(size_t)(int)pk.y * D + lane]), aj, accP);
        ++eP;
    }
#pragma unroll 4
    while (eN < endN) {
        uint2 pk = e_pack[eN];
        float aj = __uint_as_float(pk.x);
        sN += aj;
        accN = fmaf(bf2f(feat16[(size_t)(int)pk.y * D + lane]), aj, accN);
        ++eN;
    }

    h_pos[(size_t)node * D + lane] = f2bf(accP / (sP + 1e-16f));
    h_neg[(size_t)node * D + lane] = f2bf(accN / (sN + 1e-16f));
}

// ---------------------------------------------------------------------------
// Pass 5: output projection via MFMA. One wave per 16 nodes.
// A-operands are DIRECT bf16x8 loads (coef folded into Bfrag at prep).
// ---------------------------------------------------------------------------
__global__ __launch_bounds__(256) void out_gemm_mfma(
        const unsigned short* __restrict__ feat16,
        const unsigned short* __restrict__ h_pos,
        const unsigned short* __restrict__ h_neg,
        const unsigned short* __restrict__ Bfrag,
        const float* __restrict__ b_fc,
        const float* __restrict__ bias,
        float* __restrict__ out,
        int N) {
    int lane = threadIdx.x & 63;
    int wv = (blockIdx.x * blockDim.x + threadIdx.x) >> 6;
    int node0 = wv * 16;
    if (node0 >= N) return;

    const bf16x8* bp = (const bf16x8*)Bfrag;
    bf16x8 bfr[24];
#pragma unroll
    for (int f = 0; f < 24; ++f) bfr[f] = bp[f * 64 + lane];

    const unsigned short* segs[3];
    segs[0] = feat16;
    segs[1] = h_pos;
    segs[2] = h_neg;

    int m = lane & 15;          // A row / D col
    int kg = lane >> 4;         // k-group
    int node = node0 + m;
    bool mvalid = node < N;

    f32x4 acc[4];
#pragma unroll
    for (int nt = 0; nt < 4; ++nt) acc[nt] = (f32x4){0.f, 0.f, 0.f, 0.f};

#pragma unroll
    for (int kt = 0; kt < 6; ++kt) {
        int sg = kt >> 1;
        bf16x8 a;
        if (mvalid) {
            a = *(const bf16x8*)(segs[sg] + (size_t)node * D + (kt & 1) * 32 + kg * 8);
        } else {
            a = (bf16x8){0, 0, 0, 0, 0, 0, 0, 0};
        }
#pragma unroll
        for (int nt = 0; nt < 4; ++nt)
            acc[nt] = __builtin_amdgcn_mfma_f32_16x16x32_bf16(
                a, bfr[kt * 4 + nt], acc[nt], 0, 0, 0);
    }

#pragma unroll
    for (int nt = 0; nt < 4; ++nt) {
        int col = nt * 16 + m;
        float bb = b_fc[col] + bias[col];
#pragma unroll
        for (int j = 0; j < 4; ++j) {
            int row = node0 + 4 * kg + j;
            if (row < N) out[(size_t)row * OUTD + col] = acc[nt][j] + bb;
        }
    }
}

extern "C" void kernel_launch(void* const* d_in, const int* in_sizes, int n_in,
                              void* d_out, int out_size, void* d_ws, size_t ws_size,
                              hipStream_t stream) {
    const float* feat      = (const float*)d_in[0];
    const float* w         = (const float*)d_in[1];
    const float* W_fc      = (const float*)d_in[2];
    const float* b_fc      = (const float*)d_in[3];
    const float* bias      = (const float*)d_in[4];
    const float* coef_self = (const float*)d_in[5];
    const float* coef_posi = (const float*)d_in[6];
    const float* coef_nega = (const float*)d_in[7];
    const int*   src       = (const int*)d_in[8];
    const int*   dst       = (const int*)d_in[9];

    const int E = in_sizes[1];
    const int N = in_sizes[0] / D;
    const int M = 2 * N;                      // sign-split bins
    const int NB = (M + KPB - 1) / KPB;       // 196 buckets (<=256 req.)

    // Workspace layout:
    //   seg_be [M]x8B | cursorA [NB]x4 | Bfrag [12288 u16] | feat16 [N*D u16]
    //   | e_pack [NB*CAP]x8B | staged [NB*CAP]x8B | h_pos [N*D u16] | h_neg [N*D u16]
    char* ws = (char*)d_ws;
    int2*  seg_be   = (int2*)ws;
    int*   cursorA  = (int*)(ws + (size_t)M * 8);
    size_t bfrag_off = (((size_t)M * 8 + (size_t)NB * 4) + 15) & ~(size_t)15;
    unsigned short* Bfrag = (unsigned short*)(ws + bfrag_off);
    size_t feat16_off = bfrag_off + 6 * 4 * 64 * 8 * 2;
    unsigned short* feat16 = (unsigned short*)(ws + feat16_off);
    size_t epack_off = (feat16_off + (size_t)N * D * 2 + 7) & ~(size_t)7;
    uint2* e_pack  = (uint2*)(ws + epack_off);
    uint2* staged  = e_pack + (size_t)NB * CAP;
    unsigned short* h_pos = (unsigned short*)((char*)(staged + (size_t)NB * CAP));
    unsigned short* h_neg = h_pos + (size_t)N * D;

    const int ND4 = N * D / 4;
    int pb = (max(ND4, 6 * 4 * 64 * 8) + 255) / 256;
    prep_kernel<<<pb, 256, 0, stream>>>(W_fc, coef_self, coef_posi, coef_nega,
                                        feat, Bfrag, feat16, cursorA, NB, ND4);
    bin_kernel<<<(E + ABATCH - 1) / ABATCH, 256, 0, stream>>>(
        w, src, dst, cursorA, staged, E, NB);
    bucket_scatter_kernel<<<NB, 256, 0, stream>>>(cursorA, staged, seg_be,
                                                  e_pack, M);

    int nodeb = (N * 64 + 255) / 256;
    node_agg_kernel<<<nodeb, 256, 0, stream>>>(feat16, seg_be, e_pack,
                                               h_pos, h_neg, N);

    int nwaves = (N + 15) / 16;
    int gb = (nwaves + 3) / 4;  // 4 waves per 256-thread block
    out_gemm_mfma<<<gb, 256, 0, stream>>>(feat16, h_pos, h_neg, Bfrag,
                                          b_fc, bias, (float*)d_out, N);
}

// Round 21
// 78.956 us; speedup vs baseline: 1.2514x; 1.0080x over previous
//
#include <hip/hip_runtime.h>

#define D 64
#define K3 192  // 3*D
#define OUTD 64
#define KPB 512      // keys per bucket
#define KPB_LOG 9
#define NBMAX 256    // supports M <= 131072
#define ABATCH 4096  // edges per bin block (16 per thread)
#define CAP 8192     // staged/e_pack capacity per bucket (mean 4096, sigma 64)

typedef __attribute__((ext_vector_type(8))) short bf16x8;
typedef __attribute__((ext_vector_type(4))) float f32x4;

static __device__ __forceinline__ unsigned short f2bf(float f) {
    unsigned u = __float_as_uint(f);
    u += 0x7fffu + ((u >> 16) & 1u);  // round-to-nearest-even
    return (unsigned short)(u >> 16);
}
static __device__ __forceinline__ float bf2f(unsigned short h) {
    return __uint_as_float((unsigned)h << 16);
}

// ---------------------------------------------------------------------------
// Pass 0 (one-time): bake coef-scaled W_fc into MFMA B-fragment layout (bf16),
// convert feat -> bf16, init per-bucket staging cursors. No memsets anywhere.
// ---------------------------------------------------------------------------
__global__ __launch_bounds__(256) void prep_kernel(
        const float* __restrict__ W_fc,
        const float* __restrict__ coef_self,
        const float* __restrict__ coef_posi,
        const float* __restrict__ coef_nega,
        const float* __restrict__ feat,
        unsigned short* __restrict__ Bfrag,
        unsigned short* __restrict__ feat16,
        int* __restrict__ cursorA, int NB, int ND4) {
    int i = blockIdx.x * blockDim.x + threadIdx.x;
    if (i < NB) cursorA[i] = i * CAP;
    if (i < 6 * 4 * 64 * 8) {
        int j    = i & 7;
        int lane = (i >> 3) & 63;
        int nt   = (i >> 9) & 3;
        int kt   = i >> 11;
        int n = nt * 16 + (lane & 15);
        int k = kt * 32 + (lane >> 4) * 8 + j;
        float cf = (k < 64) ? coef_self[0] : (k < 128 ? coef_posi[0] : coef_nega[0]);
        Bfrag[i] = f2bf(W_fc[n * K3 + k] * cf);
    }
    if (i < ND4) {  // 4 feats per thread
        float4 v = *(const float4*)&feat[(size_t)i * 4];
        unsigned long long p =
            (unsigned long long)f2bf(v.x) |
            ((unsigned long long)f2bf(v.y) << 16) |
            ((unsigned long long)f2bf(v.z) << 32) |
            ((unsigned long long)f2bf(v.w) << 48);
        *(unsigned long long*)&feat16[(size_t)i * 4] = p;
    }
}

// ---------------------------------------------------------------------------
// Pass A: bin edges into fixed-capacity bucket staging.
// bucket = key >> 9, key = 2*dst + (w<0).
// Record: x = w bits, y = (src << 9) | (key & 511).
// ---------------------------------------------------------------------------
__global__ __launch_bounds__(256) void bin_kernel(
        const float* __restrict__ w, const int* __restrict__ src,
        const int* __restrict__ dst, int* __restrict__ cursorA,
        uint2* __restrict__ staged, int E, int NB) {
    __shared__ int cnt[NBMAX];
    __shared__ int base[NBMAX];
    int t = threadIdx.x;
    int e0 = blockIdx.x * ABATCH;
    for (int i = t; i < NB; i += 256) cnt[i] = 0;
    __syncthreads();

    unsigned wv[16], yv[16];
    int bk[16], rk[16];
#pragma unroll
    for (int j = 0; j < 16; ++j) {
        int e = e0 + j * 256 + t;  // coalesced per round
        if (e < E) {
            float we = w[e];
            int key = 2 * dst[e] + (we < 0.0f ? 1 : 0);
            wv[j] = __float_as_uint(we);
            yv[j] = ((unsigned)src[e] << KPB_LOG) | (unsigned)(key & (KPB - 1));
            bk[j] = key >> KPB_LOG;
            rk[j] = atomicAdd(&cnt[bk[j]], 1);
        } else {
            bk[j] = -1;
        }
    }
    __syncthreads();
    for (int b = t; b < NB; b += 256) {
        int c = cnt[b];
        if (c > 0) base[b] = atomicAdd(&cursorA[b], c);
    }
    __syncthreads();
#pragma unroll
    for (int j = 0; j < 16; ++j) {
        if (bk[j] >= 0) {
            int pos = base[bk[j]] + rk[j];
            if (pos < (bk[j] + 1) * CAP)  // defensive (60-sigma event)
                staged[pos] = make_uint2(wv[j], yv[j]);
        }
    }
}

// ---------------------------------------------------------------------------
// Pass B: per-bucket fused key-hist + scan + scatter. One block per bucket.
// Final record: (w bits, src).
// ---------------------------------------------------------------------------
__global__ __launch_bounds__(256) void bucket_scatter_kernel(
        const int* __restrict__ cursorA, const uint2* __restrict__ staged,
        int2* __restrict__ seg_be, uint2* __restrict__ e_pack, int M) {
    __shared__ int cnt[KPB];   // counts, then cursors
    __shared__ int wt[4];
    int b = blockIdx.x;
    int t = threadIdx.x;
    int lane = t & 63;
    int wid = t >> 6;
    int kb = b << KPB_LOG;
    int nk = min(KPB, M - kb);
    int beg = b * CAP;
    int end = min(cursorA[b], beg + CAP);  // cursor = base + count

    cnt[2 * t] = 0;
    cnt[2 * t + 1] = 0;
    __syncthreads();
    for (int i = beg + t; i < end; i += 256)
        atomicAdd(&cnt[staged[i].y & (KPB - 1)], 1);
    __syncthreads();

    // block exclusive scan of 512 counts (2 per thread)
    int v0 = cnt[2 * t], v1 = cnt[2 * t + 1];
    int ps = v0 + v1;
    int incl = ps;
#pragma unroll
    for (int o = 1; o < 64; o <<= 1) {
        int u = __shfl_up(incl, o);
        if (lane >= o) incl += u;
    }
    if (lane == 63) wt[wid] = incl;
    __syncthreads();
    int wb = 0;
    for (int j = 0; j < wid; ++j) wb += wt[j];
    int excl = wb + (incl - ps);

    int p0 = beg + excl;
    int p1 = p0 + v0;
    if (2 * t < nk) seg_be[kb + 2 * t] = make_int2(p0, p1);
    if (2 * t + 1 < nk) seg_be[kb + 2 * t + 1] = make_int2(p1, p1 + v1);
    __syncthreads();
    cnt[2 * t] = p0;      // reuse as cursors
    cnt[2 * t + 1] = p1;
    __syncthreads();

    for (int i = beg + t; i < end; i += 256) {
        uint2 r = staged[i];
        int kl = (int)(r.y & (KPB - 1));
        int p = atomicAdd(&cnt[kl], 1);
        e_pack[p] = make_uint2(r.x, r.y >> KPB_LOG);
    }
}

// ---------------------------------------------------------------------------
// Pass 4: aggregation. ONE WAVE PER NODE (both sign segs, interleaved).
// Proven-best structure (R18): wave-uniform s_load of e_pack, v_exp, v_fmac;
// interleaved pos/neg chains give 4 independent s_load->gather chains/wave.
// Sign-split bins: no max-subtraction needed (softmax shift-invariance,
// |w| < ~6 safe in f32). Empty seg -> s=0 -> h=0 (matches ref).
// ---------------------------------------------------------------------------
__global__ __launch_bounds__(256) void node_agg_kernel(
        const unsigned short* __restrict__ feat16,
        const int2* __restrict__ seg_be,  // len 2N
        const uint2* __restrict__ e_pack,
        unsigned short* __restrict__ h_pos,
        unsigned short* __restrict__ h_neg, int N) {
    int lane = threadIdx.x & 63;
    int node = (blockIdx.x * blockDim.x + threadIdx.x) >> 6;
    if (node >= N) return;
    int4 be = *(const int4*)&seg_be[2 * node];  // 16B-aligned (2 int2)
    int eP   = __builtin_amdgcn_readfirstlane(be.x);
    int endP = __builtin_amdgcn_readfirstlane(be.y);
    int eN   = __builtin_amdgcn_readfirstlane(be.z);
    int endN = __builtin_amdgcn_readfirstlane(be.w);

    float sP = 0.0f, accP = 0.0f, sN = 0.0f, accN = 0.0f;

    // interleaved main loop: one pos edge + one neg edge per step (all
    // control wave-uniform; two independent dependency chains)
#pragma unroll 2
    while (eP < endP && eN < endN) {
        uint2 pkP = e_pack[eP];            // s_load
        uint2 pkN = e_pack[eN];            // s_load (independent)
        float wP = __uint_as_float(pkP.x); // >= 0
        float wN = __uint_as_float(pkN.x); // < 0
        float aP = (wP > 0.0f) ? __expf(wP) : 0.0f;  // exclude w==0
        float aN = __expf(-wN);
        sP += aP;
        sN += aN;
        accP = fmaf(bf2f(feat16[(size_t)(int)pkP.y * D + lane]), aP, accP);
        accN = fmaf(bf2f(feat16[(size_t)(int)pkN.y * D + lane]), aN, accN);
        ++eP;
        ++eN;
    }
    // tails
#pragma unroll 4
    while (eP < endP) {
        uint2 pk = e_pack[eP];
        float wj = __uint_as_float(pk.x);
        float aj = (wj > 0.0f) ? __expf(wj) : 0.0f;
        sP += aj;
        accP = fmaf(bf2f(feat16[(size_t)(int)pk.y * D + lane]), aj, accP);
        ++eP;
    }
#pragma unroll 4
    while (eN < endN) {
        uint2 pk = e_pack[eN];
        float wj = __uint_as_float(pk.x);
        float aj = __expf(-wj);
        sN += aj;
        accN = fmaf(bf2f(feat16[(size_t)(int)pk.y * D + lane]), aj, accN);
        ++eN;
    }

    h_pos[(size_t)node * D + lane] = f2bf(accP / (sP + 1e-16f));
    h_neg[(size_t)node * D + lane] = f2bf(accN / (sN + 1e-16f));
}

// ---------------------------------------------------------------------------
// Pass 5: output projection via MFMA. One wave per 16 nodes.
// A-operands are DIRECT bf16x8 loads (coef folded into Bfrag at prep).
// ---------------------------------------------------------------------------
__global__ __launch_bounds__(256) void out_gemm_mfma(
        const unsigned short* __restrict__ feat16,
        const unsigned short* __restrict__ h_pos,
        const unsigned short* __restrict__ h_neg,
        const unsigned short* __restrict__ Bfrag,
        const float* __restrict__ b_fc,
        const float* __restrict__ bias,
        float* __restrict__ out,
        int N) {
    int lane = threadIdx.x & 63;
    int wv = (blockIdx.x * blockDim.x + threadIdx.x) >> 6;
    int node0 = wv * 16;
    if (node0 >= N) return;

    const bf16x8* bp = (const bf16x8*)Bfrag;
    bf16x8 bfr[24];
#pragma unroll
    for (int f = 0; f < 24; ++f) bfr[f] = bp[f * 64 + lane];

    const unsigned short* segs[3];
    segs[0] = feat16;
    segs[1] = h_pos;
    segs[2] = h_neg;

    int m = lane & 15;          // A row / D col
    int kg = lane >> 4;         // k-group
    int node = node0 + m;
    bool mvalid = node < N;

    f32x4 acc[4];
#pragma unroll
    for (int nt = 0; nt < 4; ++nt) acc[nt] = (f32x4){0.f, 0.f, 0.f, 0.f};

#pragma unroll
    for (int kt = 0; kt < 6; ++kt) {
        int sg = kt >> 1;
        bf16x8 a;
        if (mvalid) {
            a = *(const bf16x8*)(segs[sg] + (size_t)node * D + (kt & 1) * 32 + kg * 8);
        } else {
            a = (bf16x8){0, 0, 0, 0, 0, 0, 0, 0};
        }
#pragma unroll
        for (int nt = 0; nt < 4; ++nt)
            acc[nt] = __builtin_amdgcn_mfma_f32_16x16x32_bf16(
                a, bfr[kt * 4 + nt], acc[nt], 0, 0, 0);
    }

#pragma unroll
    for (int nt = 0; nt < 4; ++nt) {
        int col = nt * 16 + m;
        float bb = b_fc[col] + bias[col];
#pragma unroll
        for (int j = 0; j < 4; ++j) {
            int row = node0 + 4 * kg + j;
            if (row < N) out[(size_t)row * OUTD + col] = acc[nt][j] + bb;
        }
    }
}

extern "C" void kernel_launch(void* const* d_in, const int* in_sizes, int n_in,
                              void* d_out, int out_size, void* d_ws, size_t ws_size,
                              hipStream_t stream) {
    const float* feat      = (const float*)d_in[0];
    const float* w         = (const float*)d_in[1];
    const float* W_fc      = (const float*)d_in[2];
    const float* b_fc      = (const float*)d_in[3];
    const float* bias      = (const float*)d_in[4];
    const float* coef_self = (const float*)d_in[5];
    const float* coef_posi = (const float*)d_in[6];
    const float* coef_nega = (const float*)d_in[7];
    const int*   src       = (const int*)d_in[8];
    const int*   dst       = (const int*)d_in[9];

    const int E = in_sizes[1];
    const int N = in_sizes[0] / D;
    const int M = 2 * N;                      // sign-split bins
    const int NB = (M + KPB - 1) / KPB;       // 196 buckets (<=256 req.)

    // Workspace layout:
    //   seg_be [M]x8B | cursorA [NB]x4 | Bfrag [12288 u16] | feat16 [N*D u16]
    //   | e_pack [NB*CAP]x8B | staged [NB*CAP]x8B | h_pos [N*D u16] | h_neg [N*D u16]
    char* ws = (char*)d_ws;
    int2*  seg_be   = (int2*)ws;
    int*   cursorA  = (int*)(ws + (size_t)M * 8);
    size_t bfrag_off = (((size_t)M * 8 + (size_t)NB * 4) + 15) & ~(size_t)15;
    unsigned short* Bfrag = (unsigned short*)(ws + bfrag_off);
    size_t feat16_off = bfrag_off + 6 * 4 * 64 * 8 * 2;
    unsigned short* feat16 = (unsigned short*)(ws + feat16_off);
    size_t epack_off = (feat16_off + (size_t)N * D * 2 + 7) & ~(size_t)7;
    uint2* e_pack  = (uint2*)(ws + epack_off);
    uint2* staged  = e_pack + (size_t)NB * CAP;
    unsigned short* h_pos = (unsigned short*)((char*)(staged + (size_t)NB * CAP));
    unsigned short* h_neg = h_pos + (size_t)N * D;

    const int ND4 = N * D / 4;
    int pb = (max(ND4, 6 * 4 * 64 * 8) + 255) / 256;
    prep_kernel<<<pb, 256, 0, stream>>>(W_fc, coef_self, coef_posi, coef_nega,
                                        feat, Bfrag, feat16, cursorA, NB, ND4);
    bin_kernel<<<(E + ABATCH - 1) / ABATCH, 256, 0, stream>>>(
        w, src, dst, cursorA, staged, E, NB);
    bucket_scatter_kernel<<<NB, 256, 0, stream>>>(cursorA, staged, seg_be,
                                                  e_pack, M);

    int nodeb = (N * 64 + 255) / 256;
    node_agg_kernel<<<nodeb, 256, 0, stream>>>(feat16, seg_be, e_pack,
                                               h_pos, h_neg, N);

    int nwaves = (N + 15) / 16;
    int gb = (nwaves + 3) / 4;  // 4 waves per 256-thread block
    out_gemm_mfma<<<gb, 256, 0, stream>>>(feat16, h_pos, h_neg, Bfrag,
                                          b_fc, bias, (float*)d_out, N);
}